// Round 8
// baseline (203.089 us; speedup 1.0000x reference)
//
#include <hip/hip_runtime.h>
#include <math.h>

#define NPART 8192
#define R2c   0.0025f     /* RADIUS^2 (float32(0.05^2)) */
#define CR2c  0.01f       /* (2*RADIUS)^2 */
#define ACCS  0.005f
#define MAXV  0.05f
#define EPSV  1e-06f
#define NB1D  20          /* bins per axis, width 0.1 over [-1,1] */
#define NBINS 400
#define NPREP 32          /* prep blocks (per-block histograms) */
#define NSEG  8           /* scatter segments per bin (1024 rows each) */
#define SWBLK 2048        /* sweep blocks: 4 waves = 4 sorted slots each */
#define OUT_SCALARS 57344 /* offset of the 6 scalar outputs in d_out */

#define WRED(v) do { \
    v += __shfl_xor(v, 32); v += __shfl_xor(v, 16); v += __shfl_xor(v, 8); \
    v += __shfl_xor(v, 4);  v += __shfl_xor(v, 2);  v += __shfl_xor(v, 1); \
  } while (0)

// ---------------------------------------------------------------- K1 ------
// prep + per-block histogram. Per row: 32B record {px,py,y0,y1|y2,y3,ci,orig}
// + bin id. Each block LDS-histograms its 256 rows and writes the transposed
// per-block counts bhistT[bin*32+blk] (every entry written -> no zero pass,
// no global atomics, fully deterministic). Block 0 also re-zeroes the sweep
// accumulators + ticket (graph replays don't re-poison ws).
__global__ __launch_bounds__(256) void prep_kernel(
    const float* __restrict__ x, const float* __restrict__ wn,
    float4* __restrict__ rec, int* __restrict__ binid,
    int* __restrict__ bhistT, unsigned long long* __restrict__ acc,
    unsigned int* __restrict__ ticket)
{
  __shared__ int h[NBINS];
  const int t = threadIdx.x;
  h[t] = 0;
  if (t + 256 < NBINS) h[t + 256] = 0;
  if (blockIdx.x == 0) {
    if (t < 6) acc[t] = 0ull;
    if (t == 6) *ticket = 0u;
  }
  __syncthreads();

  const int i = blockIdx.x * 256 + t;
  const float* xi = x + i * 7;
  float v0 = xi[0], v1 = xi[1], v2 = xi[2], v3 = xi[3];
  float v4 = xi[4], v5 = xi[5], v6 = xi[6];
  float ci = (v4 > 0.5f) ? 1.0f : 0.0f;
  float y[4];
#pragma unroll
  for (int c = 0; c < 4; ++c) {
    float s = v0 * wn[c];
    s += v1 * wn[4 + c];
    s += v2 * wn[8 + c];
    s += v3 * wn[12 + c];
    s += v4 * wn[16 + c];
    s += v5 * wn[20 + c];
    s += v6 * wn[24 + c];
    y[c] = s;
  }
  int bx = (int)floorf((v0 + 1.0f) * 10.0f); bx = bx < 0 ? 0 : (bx > 19 ? 19 : bx);
  int by = (int)floorf((v1 + 1.0f) * 10.0f); by = by < 0 ? 0 : (by > 19 ? 19 : by);
  const int bid = by * NB1D + bx;
  binid[i] = bid;
  rec[i * 2]     = make_float4(v0, v1, y[0], y[1]);
  rec[i * 2 + 1] = make_float4(y[2], y[3], ci, __int_as_float(i));
  atomicAdd(&h[bid], 1); /* LDS atomic, order-independent count */
  __syncthreads();

  bhistT[t * NPREP + blockIdx.x] = h[t];
  if (t + 256 < NBINS) bhistT[(t + 256) * NPREP + blockIdx.x] = h[t + 256];
}

// ---------------------------------------------------------------- K2 ------
// scan + stable scatter, 8 segment-waves per bin (3200 waves, 800 blocks).
// Wave (b,q) derives its start rank from bhistT: rank = sum(bins<b, all 32
// prep-blocks) + sum(bin b, prep-blocks < 4q), then scans only segment q
// (1024 rows, 4 chunk iters). Stable order preserved -> identical sorted
// layout, fully deterministic.
__global__ __launch_bounds__(256) void scatter_kernel(
    const int* __restrict__ binid, const int* __restrict__ bhistT,
    const float4* __restrict__ rec, float4* __restrict__ srec,
    int* __restrict__ binstart)
{
  const int lane = threadIdx.x & 63, wave = threadIdx.x >> 6;
  const int gw = blockIdx.x * 4 + wave;
  const int b = gw >> 3;   /* bin       */
  const int q = gw & 7;    /* segment   */

  int accLT = 0, accEQpre = 0, accEQfull = 0, accSeg = 0;
#pragma unroll
  for (int k = 0; k < 7; ++k) {
    int idx = k * 64 + lane;
    if (idx < NBINS && idx <= b) {
      const int4* hp = (const int4*)(bhistT + idx * NPREP);
      int sAll = 0, sPre = 0, sSeg = 0;
#pragma unroll
      for (int m = 0; m < 8; ++m) {  /* int4 m = prep-blocks 4m..4m+3 = seg m */
        int4 v = hp[m];
        int sm = v.x + v.y + v.z + v.w;
        sAll += sm;
        sPre += (m < q) ? sm : 0;
        sSeg += (m == q) ? sm : 0;
      }
      if (idx < b) accLT += sAll;
      else { accEQpre = sPre; accEQfull = sAll; accSeg = sSeg; }
    }
  }
  WRED(accLT); WRED(accEQpre); WRED(accEQfull); WRED(accSeg);

  if (q == 0 && lane == 0) {
    binstart[b] = accLT;
    if (b == NBINS - 1) binstart[NBINS] = accLT + accEQfull;
  }
  if (accSeg == 0) return;

  int rank = accLT + accEQpre;
  const int cbeg = q * 1024;
  for (int c = cbeg; c < cbeg + 1024; c += 256) {
    int i0 = binid[c + lane];
    int i1 = binid[c + 64 + lane];
    int i2 = binid[c + 128 + lane];
    int i3 = binid[c + 192 + lane];
#define STEP(II, CC) { \
      unsigned long long m = __ballot((II) == b); \
      if ((II) == b) { \
        int my = rank + __popcll(m & ((1ull << lane) - 1ull)); \
        srec[my * 2]     = rec[((CC) + lane) * 2]; \
        srec[my * 2 + 1] = rec[((CC) + lane) * 2 + 1]; \
      } \
      rank += __popcll(m); }
    STEP(i0, c) STEP(i1, c + 64) STEP(i2, c + 128) STEP(i3, c + 192)
#undef STEP
  }
}

// ---------------------------------------------------------------- K3 ------
// sweep + FUSED scalar reduction (R8): no reduce kernel, no fences (R5
// lesson: per-block device fences force L2 writebacks, ~40us/2048 blocks).
// All cross-block data flows through device-scope ATOMICS ONLY (RMW at the
// coherence point): each block adds fixed-point int64 partials (exact-pow2
// scale -> order-independent integer sums = bit-deterministic), orders its
// ticket increment after the adds via a TRUE DATA DEPENDENCY on the atomic
// return values (opaque v_and_b32), and the last ticket holder reads the
// accumulators back with atomicAdd(p,0) and writes the 6 floats.
// Counts are packed 2^0/2^8/2^16 into ONE accumulator (values <256, sums
// <2^24 -> exact) so the wave reduce is 5 WREDs instead of 7.
__global__ __launch_bounds__(256, 8) void sweep_kernel(
    const float* __restrict__ x, const float* __restrict__ wself,
    const float* __restrict__ bvec, const int* __restrict__ binstart,
    const float4* __restrict__ srec, float* __restrict__ out,
    unsigned long long* __restrict__ acc, unsigned int* __restrict__ ticket)
{
  __shared__ float s_scal[4][6];
  const int lane = threadIdx.x & 63, wave = threadIdx.x >> 6;
  const int s = blockIdx.x * 4 + wave;
  const float4 r0 = srec[s * 2];
  const float4 r1 = srec[s * 2 + 1];
  const float px = r0.x, py = r0.y, ci = r1.z;
  const int orig = __float_as_int(r1.w);
  int bx = (int)floorf((px + 1.0f) * 10.0f); bx = bx < 0 ? 0 : (bx > 19 ? 19 : bx);
  int by = (int)floorf((py + 1.0f) * 10.0f); by = by < 0 ? 0 : (by > 19 ? 19 : by);
  const int xlo = (bx > 0) ? bx - 1 : 0, xhi = (bx < 19) ? bx + 1 : 19;
  const int rm = by - 1, rp = by + 1;
  const int b0 = (rm >= 0) ? binstart[rm * NB1D + xlo] : 0;
  const int e0 = (rm >= 0) ? binstart[rm * NB1D + xhi + 1] : 0;
  const int b1 = binstart[by * NB1D + xlo];
  const int e1 = binstart[by * NB1D + xhi + 1];
  const int b2 = (rp < NB1D) ? binstart[rp * NB1D + xlo] : 0;
  const int e2 = (rp < NB1D) ? binstart[rp * NB1D + xhi + 1] : 0;
  const int len0 = e0 - b0, len1 = e1 - b1;
  const int total = len0 + len1 + (e2 - b2);

  /* ordinal o -> sorted index (2 selects; lens are wave-uniform) */
#define IA(O, DST) { int t1 = (O) - len0, t2 = (O) - len0 - len1; \
    DST = b0 + (O); DST = (t1 >= 0) ? (b1 + t1) : DST; \
    DST = (t2 >= 0) ? (b2 + t2) : DST; }

  float nsx = 0.f, nsy = 0.f, nsz = 0.f, nsw = 0.f;
  float pk = 0.f; /* cons*2^16 + cnb*2^8 + cnt (all <256 -> exact) */

  int o = lane;
  bool v = o < total;
  int ia; IA(v ? o : 0, ia); if (!v) ia = 0;
  float4 a0 = srec[ia * 2];
  float4 a1 = srec[ia * 2 + 1];
  const int nchunk = (total + 63) >> 6;
  for (int k = 0; k < nchunk; ++k) {
    int on = o + 64;
    bool vn = on < total;
    int ian; IA(vn ? on : 0, ian); if (!vn) ian = 0;
    float4 n0 = srec[ian * 2];          /* prefetch next chunk */
    float4 n1 = srec[ian * 2 + 1];
    float dx = __fsub_rn(px, a0.x), dy = __fsub_rn(py, a0.y);
    float d2 = __fadd_rn(__fmul_rn(dx, dx), __fmul_rn(dy, dy));
    bool valid = v && (__float_as_int(a1.w) != orig);
    bool inCR = valid && (d2 < CR2c);
    bool inR  = valid && (d2 < R2c);
    float cj = a1.z;
    pk += (inCR ? cj * 65536.f : 0.f) + (inR ? (cj * 256.f + 1.f) : 0.f);
    nsx += inR ? a0.z : 0.f;
    nsy += inR ? a0.w : 0.f;
    nsz += inR ? a1.x : 0.f;
    nsw += inR ? a1.y : 0.f;
    o = on; v = vn; a0 = n0; a1 = n1;
  }
#undef IA

  WRED(nsx); WRED(nsy); WRED(nsz); WRED(nsw); WRED(pk);

  if (lane == 0) {
    /* exact unpack (all fields integer-valued, < 2^24) */
    float consCR = floorf(pk * 1.52587890625e-05f);      /* 2^-16 */
    float rem = pk - consCR * 65536.f;
    float cnbR = floorf(rem * 0.00390625f);              /* 2^-8  */
    float cntR = rem - cnbR * 256.f;

    const float* xi = x + orig * 7;
    float vx = xi[2], vy = xi[3], typ = xi[4], x5 = xi[5], x6 = xi[6];
    float h0 = bvec[0] + px * wself[0] + py * wself[4] + vx * wself[8] +
               vy * wself[12] + typ * wself[16] + x5 * wself[20] +
               x6 * wself[24] + nsx;
    float h1 = bvec[1] + px * wself[1] + py * wself[5] + vx * wself[9] +
               vy * wself[13] + typ * wself[17] + x5 * wself[21] +
               x6 * wself[25] + nsy;
    float h2 = bvec[2] + px * wself[2] + py * wself[6] + vx * wself[10] +
               vy * wself[14] + typ * wself[18] + x5 * wself[22] +
               x6 * wself[26] + nsz;
    float h3 = bvec[3] + px * wself[3] + py * wself[7] + vx * wself[11] +
               vy * wself[15] + typ * wself[19] + x5 * wself[23] +
               x6 * wself[27] + nsw;
    float scm = ACCS * ci;
    h0 *= scm; h1 *= scm; h2 *= scm; h3 *= scm;
    float nvx = fminf(fmaxf(vx + h0, -MAXV), MAXV);
    float nvy = fminf(fmaxf(vy + h1, -MAXV), MAXV);
    float npx = px + nvx, npy = py + nvy;
    float border = 0.f;
    float ax = fabsf(npx), ay = fabsf(npy);
    if (ax > 1.0f) border += logf(ax + EPSV);
    if (ay > 1.0f) border += logf(ay + EPSV);
    bool dead = (ci > 0.5f) && (cnbR < 2.5f);
    bool consumed = (ci < 0.5f) && (consCR > 4.5f);
    float keep = (dead || consumed) ? 0.f : 1.f;
    float* orow = out + (size_t)orig * 7;
    orow[0] = npx * keep; orow[1] = npy * keep;
    orow[2] = nvx * keep; orow[3] = nvy * keep;
    orow[4] = typ * keep; orow[5] = h2 * keep; orow[6] = h3 * keep;
    s_scal[wave][0] = fabsf(nvx);
    s_scal[wave][1] = fabsf(nvy);
    s_scal[wave][2] = border;
    s_scal[wave][3] = consumed ? 1.f : 0.f;
    s_scal[wave][4] = dead ? 1.f : 0.f;
    s_scal[wave][5] = cntR - cnbR;
  }
  __syncthreads();
  if (threadIdx.x == 0) {
    float t0 = s_scal[0][0] + s_scal[1][0] + s_scal[2][0] + s_scal[3][0];
    float t1 = s_scal[0][1] + s_scal[1][1] + s_scal[2][1] + s_scal[3][1];
    float t2 = s_scal[0][2] + s_scal[1][2] + s_scal[2][2] + s_scal[3][2];
    float t3 = s_scal[0][3] + s_scal[1][3] + s_scal[2][3] + s_scal[3][3];
    float t4 = s_scal[0][4] + s_scal[1][4] + s_scal[2][4] + s_scal[3][4];
    float t5 = s_scal[0][5] + s_scal[1][5] + s_scal[2][5] + s_scal[3][5];
    /* fixed-point: exact pow2 scale, llrintf deterministic */
    unsigned long long q0 = (unsigned long long)(long long)llrintf(t0 * 16777216.f);
    unsigned long long q1 = (unsigned long long)(long long)llrintf(t1 * 16777216.f);
    unsigned long long q2 = (unsigned long long)(long long)llrintf(t2 * 16777216.f);
    unsigned long long q3 = (unsigned long long)(long long)llrintf(t3);
    unsigned long long q4 = (unsigned long long)(long long)llrintf(t4);
    unsigned long long q5 = (unsigned long long)(long long)llrintf(t5);
    unsigned long long r0 = atomicAdd(&acc[0], q0);
    unsigned long long r1 = atomicAdd(&acc[1], q1);
    unsigned long long r2 = atomicAdd(&acc[2], q2);
    unsigned long long r3 = atomicAdd(&acc[3], q3);
    unsigned long long r4 = atomicAdd(&acc[4], q4);
    unsigned long long r5 = atomicAdd(&acc[5], q5);
    /* order ticket AFTER the adds via true data dependency (no fence) */
    unsigned fl = (unsigned)(r0 + r1 + r2 + r3 + r4 + r5);
    unsigned zero;
    asm volatile("v_and_b32 %0, 0, %1" : "=v"(zero) : "v"(fl));
    unsigned old = atomicAdd(ticket, 1u + zero);
    if (old == SWBLK - 1) {
      unsigned long long a0 = atomicAdd(&acc[0], 0ull);
      unsigned long long a1 = atomicAdd(&acc[1], 0ull);
      unsigned long long a2 = atomicAdd(&acc[2], 0ull);
      unsigned long long a3 = atomicAdd(&acc[3], 0ull);
      unsigned long long a4 = atomicAdd(&acc[4], 0ull);
      unsigned long long a5 = atomicAdd(&acc[5], 0ull);
      /* vel_bonus = sum/8192: 2^-24 * 2^-13 = 2^-37 */
      out[OUT_SCALARS + 0] = (float)(long long)a0 * 7.2759576141834259e-12f;
      out[OUT_SCALARS + 1] = (float)(long long)a1 * 7.2759576141834259e-12f;
      out[OUT_SCALARS + 2] = (float)(long long)a2 * 5.9604644775390625e-08f;
      out[OUT_SCALARS + 3] = (float)(long long)a3;
      out[OUT_SCALARS + 4] = (float)(long long)a4;
      out[OUT_SCALARS + 5] = (float)(long long)a5;
    }
  }
}

// ------------------------------------------------------------- launch -----
extern "C" void kernel_launch(void* const* d_in, const int* in_sizes, int n_in,
                              void* d_out, int out_size, void* d_ws, size_t ws_size,
                              hipStream_t stream)
{
  const float* x      = (const float*)d_in[0];
  const float* wself  = (const float*)d_in[1];
  const float* wneigh = (const float*)d_in[2];
  const float* bvec   = (const float*)d_in[3];
  float* out = (float*)d_out;
  float* ws  = (float*)d_ws;

  float4* rec   = (float4*)ws;                      /* 8N floats          */
  float4* srec  = (float4*)(ws + 8 * NPART);        /* 8N floats          */
  int* binid    = (int*)(ws + 16 * NPART);          /* N ints             */
  int* bhistT   = (int*)(ws + 17 * NPART);          /* NBINS*NPREP ints   */
  int* binstart = bhistT + NBINS * NPREP;           /* NBINS+1 ints       */
  unsigned long long* acc =
      (unsigned long long*)(ws + 17 * NPART + NBINS * NPREP + 416); /* 6 ull */
  unsigned int* ticket = (unsigned int*)(acc + 6);  /* 1 uint             */

  hipLaunchKernelGGL(prep_kernel, dim3(NPART / 256), dim3(256), 0, stream,
                     x, wneigh, rec, binid, bhistT, acc, ticket);
  hipLaunchKernelGGL(scatter_kernel, dim3(NBINS * NSEG / 4), dim3(256), 0, stream,
                     binid, bhistT, rec, srec, binstart);
  hipLaunchKernelGGL(sweep_kernel, dim3(SWBLK), dim3(256), 0, stream,
                     x, wself, bvec, binstart, srec, out, acc, ticket);
}

// Round 9
// 45.560 us; speedup vs baseline: 4.4577x; 4.4577x over previous
//
#include <hip/hip_runtime.h>
#include <math.h>

#define NPART 8192
#define R2c   0.0025f     /* RADIUS^2 (float32(0.05^2)) */
#define CR2c  0.01f       /* (2*RADIUS)^2 */
#define ACCS  0.005f
#define MAXV  0.05f
#define EPSV  1e-06f
#define NB1D  20          /* bins per axis, width 0.1 over [-1,1] */
#define NBINS 400
#define NPREP 32          /* prep blocks (per-block histograms) */
#define NSEG  8           /* scatter segments per bin (1024 rows each) */
#define SWBLK 2048        /* sweep blocks: 4 waves = 4 sorted slots each */
#define CAP   1024        /* staged candidates per sweep block (32KB LDS) */
#define OUT_SCALARS 57344 /* offset of the 6 scalar outputs in d_out */

#define WRED(v) do { \
    v += __shfl_xor(v, 32); v += __shfl_xor(v, 16); v += __shfl_xor(v, 8); \
    v += __shfl_xor(v, 4);  v += __shfl_xor(v, 2);  v += __shfl_xor(v, 1); \
  } while (0)

// ---------------------------------------------------------------- K1 ------
// prep + per-block histogram. Per row: 32B record {px,py,y0,y1|y2,y3,ci,orig}
// + bin id. Each block LDS-histograms its 256 rows and writes the transposed
// per-block counts bhistT[bin*32+blk] (every entry written -> no zero pass,
// no global atomics, fully deterministic).
__global__ __launch_bounds__(256) void prep_kernel(
    const float* __restrict__ x, const float* __restrict__ wn,
    float4* __restrict__ rec, int* __restrict__ binid,
    int* __restrict__ bhistT)
{
  __shared__ int h[NBINS];
  const int t = threadIdx.x;
  h[t] = 0;
  if (t + 256 < NBINS) h[t + 256] = 0;
  __syncthreads();

  const int i = blockIdx.x * 256 + t;
  const float* xi = x + i * 7;
  float v0 = xi[0], v1 = xi[1], v2 = xi[2], v3 = xi[3];
  float v4 = xi[4], v5 = xi[5], v6 = xi[6];
  float ci = (v4 > 0.5f) ? 1.0f : 0.0f;
  float y[4];
#pragma unroll
  for (int c = 0; c < 4; ++c) {
    float s = v0 * wn[c];
    s += v1 * wn[4 + c];
    s += v2 * wn[8 + c];
    s += v3 * wn[12 + c];
    s += v4 * wn[16 + c];
    s += v5 * wn[20 + c];
    s += v6 * wn[24 + c];
    y[c] = s;
  }
  int bx = (int)floorf((v0 + 1.0f) * 10.0f); bx = bx < 0 ? 0 : (bx > 19 ? 19 : bx);
  int by = (int)floorf((v1 + 1.0f) * 10.0f); by = by < 0 ? 0 : (by > 19 ? 19 : by);
  const int bid = by * NB1D + bx;
  binid[i] = bid;
  rec[i * 2]     = make_float4(v0, v1, y[0], y[1]);
  rec[i * 2 + 1] = make_float4(y[2], y[3], ci, __int_as_float(i));
  atomicAdd(&h[bid], 1); /* LDS atomic, order-independent count */
  __syncthreads();

  bhistT[t * NPREP + blockIdx.x] = h[t];
  if (t + 256 < NBINS) bhistT[(t + 256) * NPREP + blockIdx.x] = h[t + 256];
}

// ---------------------------------------------------------------- K2 ------
// scan + stable scatter, 8 segment-waves per bin (3200 waves, 800 blocks).
// Wave (b,q) derives its start rank from bhistT, then scans only segment q
// (1024 rows, 4 chunk iters). Stable order preserved -> identical sorted
// layout, fully deterministic.
__global__ __launch_bounds__(256) void scatter_kernel(
    const int* __restrict__ binid, const int* __restrict__ bhistT,
    const float4* __restrict__ rec, float4* __restrict__ srec,
    int* __restrict__ binstart)
{
  const int lane = threadIdx.x & 63, wave = threadIdx.x >> 6;
  const int gw = blockIdx.x * 4 + wave;
  const int b = gw >> 3;   /* bin       */
  const int q = gw & 7;    /* segment   */

  int accLT = 0, accEQpre = 0, accEQfull = 0, accSeg = 0;
#pragma unroll
  for (int k = 0; k < 7; ++k) {
    int idx = k * 64 + lane;
    if (idx < NBINS && idx <= b) {
      const int4* hp = (const int4*)(bhistT + idx * NPREP);
      int sAll = 0, sPre = 0, sSeg = 0;
#pragma unroll
      for (int m = 0; m < 8; ++m) {  /* int4 m = prep-blocks 4m..4m+3 = seg m */
        int4 v = hp[m];
        int sm = v.x + v.y + v.z + v.w;
        sAll += sm;
        sPre += (m < q) ? sm : 0;
        sSeg += (m == q) ? sm : 0;
      }
      if (idx < b) accLT += sAll;
      else { accEQpre = sPre; accEQfull = sAll; accSeg = sSeg; }
    }
  }
  WRED(accLT); WRED(accEQpre); WRED(accEQfull); WRED(accSeg);

  if (q == 0 && lane == 0) {
    binstart[b] = accLT;
    if (b == NBINS - 1) binstart[NBINS] = accLT + accEQfull;
  }
  if (accSeg == 0) return;

  int rank = accLT + accEQpre;
  const int cbeg = q * 1024;
  for (int c = cbeg; c < cbeg + 1024; c += 256) {
    int i0 = binid[c + lane];
    int i1 = binid[c + 64 + lane];
    int i2 = binid[c + 128 + lane];
    int i3 = binid[c + 192 + lane];
#define STEP(II, CC) { \
      unsigned long long m = __ballot((II) == b); \
      if ((II) == b) { \
        int my = rank + __popcll(m & ((1ull << lane) - 1ull)); \
        srec[my * 2]     = rec[((CC) + lane) * 2]; \
        srec[my * 2 + 1] = rec[((CC) + lane) * 2 + 1]; \
      } \
      rank += __popcll(m); }
    STEP(i0, c) STEP(i1, c + 64) STEP(i2, c + 128) STEP(i3, c + 192)
#undef STEP
  }
}

// ---------------------------------------------------------------- K3 ------
// sweep with BLOCK-COOPERATIVE LDS STAGING (R9). R7's sweep was ~25-28us:
// each of 8192 waves made ~6 dependent global round trips to srec/binstart
// just written by another kernel on other XCDs (~900+cy each, prefetch
// defeated by regalloc). Now: the block's 4 waves share nearly identical
// 3x3 windows -> compute the union of their 3 row-spans, stage it ONCE
// coalesced into LDS (cap 1024 recs = 32KB), then all waves sweep from LDS.
// Per-wave candidate ORDER is unchanged -> bit-identical results. Rare
// blocks with U>CAP (row-straddle, ~2%) fall back to R7's global path.
// No fences, no global atomics (R5/R8 lessons).
__global__ __launch_bounds__(256, 4) void sweep_kernel(
    const float* __restrict__ x, const float* __restrict__ wself,
    const float* __restrict__ bvec, const int* __restrict__ binstart,
    const float4* __restrict__ srec, float* __restrict__ out,
    float* __restrict__ partials)
{
  __shared__ float4 cand[2 * CAP];   /* cand[2i]=a0, cand[2i+1]=a1 : 32KB */
  __shared__ int s_seg[4][6];
  __shared__ int s_B[3], s_O[3], s_U;
  __shared__ float s_scal[4][6];

  const int lane = threadIdx.x & 63, wave = threadIdx.x >> 6;
  const int s = blockIdx.x * 4 + wave;
  const float4 r0 = srec[s * 2];
  const float4 r1 = srec[s * 2 + 1];
  const float px = r0.x, py = r0.y, ci = r1.z;
  const int orig = __float_as_int(r1.w);
  int bx = (int)floorf((px + 1.0f) * 10.0f); bx = bx < 0 ? 0 : (bx > 19 ? 19 : bx);
  int by = (int)floorf((py + 1.0f) * 10.0f); by = by < 0 ? 0 : (by > 19 ? 19 : by);
  const int xlo = (bx > 0) ? bx - 1 : 0, xhi = (bx < 19) ? bx + 1 : 19;
  const int rm = by - 1, rp = by + 1;
  const int b0 = (rm >= 0) ? binstart[rm * NB1D + xlo] : 0;
  const int e0 = (rm >= 0) ? binstart[rm * NB1D + xhi + 1] : 0;
  const int b1 = binstart[by * NB1D + xlo];
  const int e1 = binstart[by * NB1D + xhi + 1];
  const int b2 = (rp < NB1D) ? binstart[rp * NB1D + xlo] : 0;
  const int e2 = (rp < NB1D) ? binstart[rp * NB1D + xhi + 1] : 0;
  const int len0 = e0 - b0, len1 = e1 - b1;
  const int total = len0 + len1 + (e2 - b2);

  /* publish spans (sentinels for empty so min/max ignore them) */
  if (lane == 0) {
    s_seg[wave][0] = (rm >= 0) ? b0 : (1 << 28);
    s_seg[wave][1] = e0;                    /* 0 when empty */
    s_seg[wave][2] = b1;
    s_seg[wave][3] = e1;
    s_seg[wave][4] = (rp < NB1D) ? b2 : (1 << 28);
    s_seg[wave][5] = e2;
  }
  __syncthreads();
  if (threadIdx.x == 0) {
    int off = 0;
#pragma unroll
    for (int k = 0; k < 3; ++k) {
      int B = 1 << 28, E = 0;
#pragma unroll
      for (int w = 0; w < 4; ++w) {
        B = min(B, s_seg[w][2 * k]);
        E = max(E, s_seg[w][2 * k + 1]);
      }
      int L = (E > B) ? (E - B) : 0;
      s_B[k] = B; s_O[k] = off; off += L;
    }
    s_U = off;
  }
  __syncthreads();

  const int U = s_U;
  const bool fast = (U <= CAP);
  if (fast) {
    const int o1 = s_O[1], o2 = s_O[2];
    const int B0s = s_B[0], B1s = s_B[1], B2s = s_B[2];
    for (int idx = threadIdx.x; idx < U; idx += 256) {
      int k = (idx >= o1) + (idx >= o2);
      int base = (k == 0) ? B0s : (k == 1) ? B1s : B2s;
      int offk = (k == 0) ? 0 : (k == 1) ? o1 : o2;
      int g = base + (idx - offk);
      cand[idx * 2]     = srec[g * 2];
      cand[idx * 2 + 1] = srec[g * 2 + 1];
    }
  }
  __syncthreads();

  float nsx = 0.f, nsy = 0.f, nsz = 0.f, nsw = 0.f;
  float pk = 0.f; /* cons*2^16 + cnb*2^8 + cnt (all <256 -> exact) */

#define BODY(A0c, A1c, V) do { \
    float dx = __fsub_rn(px, (A0c).x), dy = __fsub_rn(py, (A0c).y); \
    float d2 = __fadd_rn(__fmul_rn(dx, dx), __fmul_rn(dy, dy)); \
    bool valid = (V) && (__float_as_int((A1c).w) != orig); \
    bool inCR = valid && (d2 < CR2c); \
    bool inR  = valid && (d2 < R2c); \
    float cj = (A1c).z; \
    pk += (inCR ? cj * 65536.f : 0.f) + (inR ? (cj * 256.f + 1.f) : 0.f); \
    nsx += inR ? (A0c).z : 0.f; \
    nsy += inR ? (A0c).w : 0.f; \
    nsz += inR ? (A1c).x : 0.f; \
    nsw += inR ? (A1c).y : 0.f; \
  } while (0)

  const int nchunk = (total + 63) >> 6;
  if (fast) {
    /* wave-local LDS bases per segment (garbage when that len==0, unused) */
    const int lb0 = s_O[0] + (b0 - s_B[0]);
    const int lb1 = s_O[1] + (b1 - s_B[1]);
    const int lb2 = s_O[2] + (b2 - s_B[2]);
    int o = lane;
    for (int k = 0; k < nchunk; ++k) {
      bool v = o < total;
      int oo = v ? o : 0;
      int t1 = oo - len0, t2 = oo - len0 - len1;
      int li = lb0 + oo;
      li = (t1 >= 0) ? (lb1 + t1) : li;
      li = (t2 >= 0) ? (lb2 + t2) : li;
      float4 a0c = cand[li * 2];
      float4 a1c = cand[li * 2 + 1];
      BODY(a0c, a1c, v);
      o += 64;
    }
  } else {
    /* rare fallback: direct global reads, identical candidate order */
    int o = lane;
    for (int k = 0; k < nchunk; ++k) {
      bool v = o < total;
      int oo = v ? o : 0;
      int t1 = oo - len0, t2 = oo - len0 - len1;
      int ia = b0 + oo;
      ia = (t1 >= 0) ? (b1 + t1) : ia;
      ia = (t2 >= 0) ? (b2 + t2) : ia;
      float4 a0c = srec[ia * 2];
      float4 a1c = srec[ia * 2 + 1];
      BODY(a0c, a1c, v);
      o += 64;
    }
  }
#undef BODY

  WRED(nsx); WRED(nsy); WRED(nsz); WRED(nsw); WRED(pk);

  if (lane == 0) {
    /* exact unpack (all fields integer-valued, < 2^24) */
    float consCR = floorf(pk * 1.52587890625e-05f);      /* 2^-16 */
    float rem = pk - consCR * 65536.f;
    float cnbR = floorf(rem * 0.00390625f);              /* 2^-8  */
    float cntR = rem - cnbR * 256.f;

    const float* xi = x + orig * 7;
    float vx = xi[2], vy = xi[3], typ = xi[4], x5 = xi[5], x6 = xi[6];
    float h0 = bvec[0] + px * wself[0] + py * wself[4] + vx * wself[8] +
               vy * wself[12] + typ * wself[16] + x5 * wself[20] +
               x6 * wself[24] + nsx;
    float h1 = bvec[1] + px * wself[1] + py * wself[5] + vx * wself[9] +
               vy * wself[13] + typ * wself[17] + x5 * wself[21] +
               x6 * wself[25] + nsy;
    float h2 = bvec[2] + px * wself[2] + py * wself[6] + vx * wself[10] +
               vy * wself[14] + typ * wself[18] + x5 * wself[22] +
               x6 * wself[26] + nsz;
    float h3 = bvec[3] + px * wself[3] + py * wself[7] + vx * wself[11] +
               vy * wself[15] + typ * wself[19] + x5 * wself[23] +
               x6 * wself[27] + nsw;
    float scm = ACCS * ci;
    h0 *= scm; h1 *= scm; h2 *= scm; h3 *= scm;
    float nvx = fminf(fmaxf(vx + h0, -MAXV), MAXV);
    float nvy = fminf(fmaxf(vy + h1, -MAXV), MAXV);
    float npx = px + nvx, npy = py + nvy;
    float border = 0.f;
    float ax = fabsf(npx), ay = fabsf(npy);
    if (ax > 1.0f) border += logf(ax + EPSV);
    if (ay > 1.0f) border += logf(ay + EPSV);
    bool dead = (ci > 0.5f) && (cnbR < 2.5f);
    bool consumed = (ci < 0.5f) && (consCR > 4.5f);
    float keep = (dead || consumed) ? 0.f : 1.f;
    float* orow = out + (size_t)orig * 7;
    orow[0] = npx * keep; orow[1] = npy * keep;
    orow[2] = nvx * keep; orow[3] = nvy * keep;
    orow[4] = typ * keep; orow[5] = h2 * keep; orow[6] = h3 * keep;
    s_scal[wave][0] = fabsf(nvx);
    s_scal[wave][1] = fabsf(nvy);
    s_scal[wave][2] = border;
    s_scal[wave][3] = consumed ? 1.f : 0.f;
    s_scal[wave][4] = dead ? 1.f : 0.f;
    s_scal[wave][5] = cntR - cnbR;
  }
  __syncthreads();
  if (threadIdx.x == 0) {
#pragma unroll
    for (int k = 0; k < 6; ++k)
      partials[blockIdx.x * 6 + k] =
          s_scal[0][k] + s_scal[1][k] + s_scal[2][k] + s_scal[3][k];
  }
}

// ---------------------------------------------------------------- K4 ------
// Deterministic reduction of the 2048x6 partials in fixed lane-strided
// order. Separate launch = cross-block visibility without fences (R5/R8
// lessons: fences AND same-line device atomics are ~10x kernel-boundary
// cost on multi-XCD gfx950).
__global__ __launch_bounds__(384) void reduce_kernel(
    const float* __restrict__ partials, float* __restrict__ out)
{
  int wave = threadIdx.x >> 6, lane = threadIdx.x & 63;
  if (wave >= 6) return;
  float s = 0.f;
  for (int bidx = lane; bidx < SWBLK; bidx += 64) s += partials[bidx * 6 + wave];
  WRED(s);
  if (lane == 0) {
    float v = s;
    if (wave < 2) v = s * (1.0f / 8192.0f); /* vel_bonus = mean */
    out[OUT_SCALARS + wave] = v;
  }
}

// ------------------------------------------------------------- launch -----
extern "C" void kernel_launch(void* const* d_in, const int* in_sizes, int n_in,
                              void* d_out, int out_size, void* d_ws, size_t ws_size,
                              hipStream_t stream)
{
  const float* x      = (const float*)d_in[0];
  const float* wself  = (const float*)d_in[1];
  const float* wneigh = (const float*)d_in[2];
  const float* bvec   = (const float*)d_in[3];
  float* out = (float*)d_out;
  float* ws  = (float*)d_ws;

  float4* rec   = (float4*)ws;                      /* 8N floats          */
  float4* srec  = (float4*)(ws + 8 * NPART);        /* 8N floats          */
  int* binid    = (int*)(ws + 16 * NPART);          /* N ints             */
  int* bhistT   = (int*)(ws + 17 * NPART);          /* NBINS*NPREP ints   */
  int* binstart = bhistT + NBINS * NPREP;           /* NBINS+1 ints       */
  float* partials = (float*)(binstart + NBINS + 65);/* SWBLK*6 floats     */

  hipLaunchKernelGGL(prep_kernel, dim3(NPART / 256), dim3(256), 0, stream,
                     x, wneigh, rec, binid, bhistT);
  hipLaunchKernelGGL(scatter_kernel, dim3(NBINS * NSEG / 4), dim3(256), 0, stream,
                     binid, bhistT, rec, srec, binstart);
  hipLaunchKernelGGL(sweep_kernel, dim3(SWBLK), dim3(256), 0, stream,
                     x, wself, bvec, binstart, srec, out, partials);
  hipLaunchKernelGGL(reduce_kernel, dim3(1), dim3(384), 0, stream,
                     partials, out);
}

// Round 10
// 35.664 us; speedup vs baseline: 5.6945x; 1.2775x over previous
//
#include <hip/hip_runtime.h>
#include <math.h>

#define NPART 8192
#define R2c   0.0025f     /* RADIUS^2 (float32(0.05^2)) */
#define CR2c  0.01f       /* (2*RADIUS)^2 */
#define ACCS  0.005f
#define MAXV  0.05f
#define EPSV  1e-06f
#define NB1D  20          /* bins per axis, width 0.1 over [-1,1] */
#define NBINS 400
#define NPREP 32          /* hist blocks (per-block histograms) */
#define SWBLK 2048        /* sweep blocks: 4 waves = 4 sorted slots each */
#define OUT_SCALARS 57344 /* offset of the 6 scalar outputs in d_out */

#define WRED(v) do { \
    v += __shfl_xor(v, 32); v += __shfl_xor(v, 16); v += __shfl_xor(v, 8); \
    v += __shfl_xor(v, 4);  v += __shfl_xor(v, 2);  v += __shfl_xor(v, 1); \
  } while (0)

__device__ __forceinline__ int binof(float v) {
  int b = (int)floorf((v + 1.0f) * 10.0f);
  return b < 0 ? 0 : (b > 19 ? 19 : b);
}

// ---------------------------------------------------------------- K1 ------
// hist only: 32 blocks LDS-histogram their 256 rows' bins, write transposed
// per-block counts bhistT[bin*32+blk]. Every entry written -> no zero pass,
// no global atomics, fully deterministic. (rec/binid writes dropped: K2
// recomputes records from x directly.)
__global__ __launch_bounds__(256) void hist_kernel(
    const float* __restrict__ x, int* __restrict__ bhistT)
{
  __shared__ int h[NBINS];
  const int t = threadIdx.x;
  h[t] = 0;
  if (t + 256 < NBINS) h[t + 256] = 0;
  __syncthreads();

  const int i = blockIdx.x * 256 + t;
  const int bid = binof(x[i * 7 + 1]) * NB1D + binof(x[i * 7]);
  atomicAdd(&h[bid], 1); /* LDS atomic, order-independent count */
  __syncthreads();

  bhistT[t * NPREP + blockIdx.x] = h[t];
  if (t + 256 < NBINS) bhistT[(t + 256) * NPREP + blockIdx.x] = h[t + 256];
}

// ---------------------------------------------------------------- K2 ------
// direct placement (replaces R7's 800-block ballot-scan scatter): 32 blocks.
// Each block: (a) reads bhistT once, coalesced; per bin computes total and
// "count in blocks < me"; (b) 512-wide Hillis-Steele inclusive scan in LDS
// -> global bin prefix; (c) recomputes its 256 rows' records from x (y =
// x@wn), gets the STABLE intra-block rank via a 256-iter LDS broadcast loop
// (rows in index order), and writes each 32B record directly to its final
// sorted slot: slot = excl[bin] + pre_blocks[bin] + rank. Identical sorted
// layout to the old counting sort -> bit-identical downstream. Block 0
// writes binstart. Fully deterministic, no global atomics.
__global__ __launch_bounds__(256) void place_kernel(
    const float* __restrict__ x, const float* __restrict__ wn,
    const int* __restrict__ bhistT, float4* __restrict__ srec,
    int* __restrict__ binstart)
{
  __shared__ int sTot[512];
  __shared__ int sIncl[512];
  __shared__ int sPre[512];
  __shared__ int sBid[256];
  const int t = threadIdx.x;
  const int me = blockIdx.x;

  /* (a) per-bin totals + blocks-before-me counts */
  for (int e = t; e < 512; e += 256) {
    int tot = 0, pre = 0;
    if (e < NBINS) {
      const int4* hp = (const int4*)(bhistT + e * NPREP);
#pragma unroll
      for (int q = 0; q < 8; ++q) {
        int4 v = hp[q];
        int b4 = q * 4;
        tot += v.x + v.y + v.z + v.w;
        pre += ((b4 + 0 < me) ? v.x : 0) + ((b4 + 1 < me) ? v.y : 0) +
               ((b4 + 2 < me) ? v.z : 0) + ((b4 + 3 < me) ? v.w : 0);
      }
    }
    sTot[e] = tot; sIncl[e] = tot; sPre[e] = pre;
  }
  __syncthreads();

  /* (b) inclusive scan over 512 (bins 400..511 are zero) */
  for (int off = 1; off < 512; off <<= 1) {
    int v0 = sIncl[t]       + ((t       >= off) ? sIncl[t - off]       : 0);
    int v1 = sIncl[t + 256] + ((t + 256 >= off) ? sIncl[t + 256 - off] : 0);
    __syncthreads();
    sIncl[t] = v0; sIncl[t + 256] = v1;
    __syncthreads();
  }

  /* (c) my row: record + bin */
  const int i = me * 256 + t;
  const float* xi = x + i * 7;
  float v0 = xi[0], v1 = xi[1], v2 = xi[2], v3 = xi[3];
  float v4 = xi[4], v5 = xi[5], v6 = xi[6];
  float ci = (v4 > 0.5f) ? 1.0f : 0.0f;
  float y[4];
#pragma unroll
  for (int c = 0; c < 4; ++c) {
    float s = v0 * wn[c];
    s += v1 * wn[4 + c];
    s += v2 * wn[8 + c];
    s += v3 * wn[12 + c];
    s += v4 * wn[16 + c];
    s += v5 * wn[20 + c];
    s += v6 * wn[24 + c];
    y[c] = s;
  }
  const int bid = binof(v1) * NB1D + binof(v0);
  sBid[t] = bid;
  __syncthreads();

  int rank = 0;
  for (int k = 0; k < 256; ++k)
    rank += (k < t && sBid[k] == bid) ? 1 : 0;  /* LDS broadcast loop */

  const int excl = sIncl[bid] - sTot[bid];
  const int slot = excl + sPre[bid] + rank;
  srec[slot * 2]     = make_float4(v0, v1, y[0], y[1]);
  srec[slot * 2 + 1] = make_float4(y[2], y[3], ci, __int_as_float(i));

  if (me == 0) {
    for (int e = t; e < NBINS; e += 256) binstart[e] = sIncl[e] - sTot[e];
    if (t == 0) binstart[NBINS] = NPART;
  }
}

// ---------------------------------------------------------------- K3 ------
// sweep (R7 global-loop form; R9's LDS staging was neutral and halved
// occupancy -> reverted). One wave per sorted slot, unified ordinal loop
// over the 3 contiguous 3x3-window segments with rolling index math. Self
// excluded via index compare; dist2 in the reference's non-contracted
// mul/mul/add form. XCD-swizzled blockIdx (2048%8==0, bijective) so
// neighboring sorted windows share an XCD L2. Partials written TRANSPOSED
// [6][SWBLK] so K4's reads are coalesced. No fences, no global atomics
// (R5/R8 lessons).
__global__ __launch_bounds__(256, 8) void sweep_kernel(
    const float* __restrict__ x, const float* __restrict__ wself,
    const float* __restrict__ bvec, const int* __restrict__ binstart,
    const float4* __restrict__ srec, float* __restrict__ out,
    float* __restrict__ partials)
{
  __shared__ float s_scal[4][6];
  const int lane = threadIdx.x & 63, wave = threadIdx.x >> 6;
  const int swz = (blockIdx.x & 7) * (SWBLK / 8) + (blockIdx.x >> 3);
  const int s = swz * 4 + wave;
  const float4 r0 = srec[s * 2];
  const float4 r1 = srec[s * 2 + 1];
  const float px = r0.x, py = r0.y, ci = r1.z;
  const int orig = __float_as_int(r1.w);
  const int bx = binof(px), by = binof(py);
  const int xlo = (bx > 0) ? bx - 1 : 0, xhi = (bx < 19) ? bx + 1 : 19;
  const int rm = by - 1, rp = by + 1;
  const int b0 = (rm >= 0) ? binstart[rm * NB1D + xlo] : 0;
  const int e0 = (rm >= 0) ? binstart[rm * NB1D + xhi + 1] : 0;
  const int b1 = binstart[by * NB1D + xlo];
  const int e1 = binstart[by * NB1D + xhi + 1];
  const int b2 = (rp < NB1D) ? binstart[rp * NB1D + xlo] : 0;
  const int e2 = (rp < NB1D) ? binstart[rp * NB1D + xhi + 1] : 0;
  const int len0 = e0 - b0, len1 = e1 - b1;
  const int total = len0 + len1 + (e2 - b2);

  /* ordinal o -> sorted index (2 selects; lens are wave-uniform) */
#define IA(O, DST) { int t1 = (O) - len0, t2 = (O) - len0 - len1; \
    DST = b0 + (O); DST = (t1 >= 0) ? (b1 + t1) : DST; \
    DST = (t2 >= 0) ? (b2 + t2) : DST; }

  float nsx = 0.f, nsy = 0.f, nsz = 0.f, nsw = 0.f;
  float pk = 0.f; /* cons*2^16 + cnb*2^8 + cnt (all <256 -> exact) */

  int o = lane;
  bool v = o < total;
  int ia; IA(v ? o : 0, ia); if (!v) ia = 0;
  float4 a0 = srec[ia * 2];
  float4 a1 = srec[ia * 2 + 1];
  const int nchunk = (total + 63) >> 6;
  for (int k = 0; k < nchunk; ++k) {
    int on = o + 64;
    bool vn = on < total;
    int ian; IA(vn ? on : 0, ian); if (!vn) ian = 0;
    float4 n0 = srec[ian * 2];          /* prefetch next chunk */
    float4 n1 = srec[ian * 2 + 1];
    float dx = __fsub_rn(px, a0.x), dy = __fsub_rn(py, a0.y);
    float d2 = __fadd_rn(__fmul_rn(dx, dx), __fmul_rn(dy, dy));
    bool valid = v && (__float_as_int(a1.w) != orig);
    bool inCR = valid && (d2 < CR2c);
    bool inR  = valid && (d2 < R2c);
    float cj = a1.z;
    pk += (inCR ? cj * 65536.f : 0.f) + (inR ? (cj * 256.f + 1.f) : 0.f);
    nsx += inR ? a0.z : 0.f;
    nsy += inR ? a0.w : 0.f;
    nsz += inR ? a1.x : 0.f;
    nsw += inR ? a1.y : 0.f;
    o = on; v = vn; a0 = n0; a1 = n1;
  }
#undef IA

  WRED(nsx); WRED(nsy); WRED(nsz); WRED(nsw); WRED(pk);

  if (lane == 0) {
    /* exact unpack (all fields integer-valued, < 2^24) */
    float consCR = floorf(pk * 1.52587890625e-05f);      /* 2^-16 */
    float rem = pk - consCR * 65536.f;
    float cnbR = floorf(rem * 0.00390625f);              /* 2^-8  */
    float cntR = rem - cnbR * 256.f;

    const float* xi = x + orig * 7;
    float vx = xi[2], vy = xi[3], typ = xi[4], x5 = xi[5], x6 = xi[6];
    float h0 = bvec[0] + px * wself[0] + py * wself[4] + vx * wself[8] +
               vy * wself[12] + typ * wself[16] + x5 * wself[20] +
               x6 * wself[24] + nsx;
    float h1 = bvec[1] + px * wself[1] + py * wself[5] + vx * wself[9] +
               vy * wself[13] + typ * wself[17] + x5 * wself[21] +
               x6 * wself[25] + nsy;
    float h2 = bvec[2] + px * wself[2] + py * wself[6] + vx * wself[10] +
               vy * wself[14] + typ * wself[18] + x5 * wself[22] +
               x6 * wself[26] + nsz;
    float h3 = bvec[3] + px * wself[3] + py * wself[7] + vx * wself[11] +
               vy * wself[15] + typ * wself[19] + x5 * wself[23] +
               x6 * wself[27] + nsw;
    float scm = ACCS * ci;
    h0 *= scm; h1 *= scm; h2 *= scm; h3 *= scm;
    float nvx = fminf(fmaxf(vx + h0, -MAXV), MAXV);
    float nvy = fminf(fmaxf(vy + h1, -MAXV), MAXV);
    float npx = px + nvx, npy = py + nvy;
    float border = 0.f;
    float ax = fabsf(npx), ay = fabsf(npy);
    if (ax > 1.0f) border += logf(ax + EPSV);
    if (ay > 1.0f) border += logf(ay + EPSV);
    bool dead = (ci > 0.5f) && (cnbR < 2.5f);
    bool consumed = (ci < 0.5f) && (consCR > 4.5f);
    float keep = (dead || consumed) ? 0.f : 1.f;
    float* orow = out + (size_t)orig * 7;
    orow[0] = npx * keep; orow[1] = npy * keep;
    orow[2] = nvx * keep; orow[3] = nvy * keep;
    orow[4] = typ * keep; orow[5] = h2 * keep; orow[6] = h3 * keep;
    s_scal[wave][0] = fabsf(nvx);
    s_scal[wave][1] = fabsf(nvy);
    s_scal[wave][2] = border;
    s_scal[wave][3] = consumed ? 1.f : 0.f;
    s_scal[wave][4] = dead ? 1.f : 0.f;
    s_scal[wave][5] = cntR - cnbR;
  }
  __syncthreads();
  if (threadIdx.x == 0) {
#pragma unroll
    for (int k = 0; k < 6; ++k)
      partials[k * SWBLK + swz] =
          s_scal[0][k] + s_scal[1][k] + s_scal[2][k] + s_scal[3][k];
  }
}

// ---------------------------------------------------------------- K4 ------
// Deterministic reduction; partials are transposed [6][SWBLK] so each
// wave's lane-strided reads are fully coalesced (8KB contiguous per wave).
// Same summation order as before -> bitwise identical. Separate launch =
// cross-block visibility without fences (R5/R8 lessons).
__global__ __launch_bounds__(384) void reduce_kernel(
    const float* __restrict__ partials, float* __restrict__ out)
{
  int wave = threadIdx.x >> 6, lane = threadIdx.x & 63;
  if (wave >= 6) return;
  float s = 0.f;
  for (int bidx = lane; bidx < SWBLK; bidx += 64)
    s += partials[wave * SWBLK + bidx];
  WRED(s);
  if (lane == 0) {
    float v = s;
    if (wave < 2) v = s * (1.0f / 8192.0f); /* vel_bonus = mean */
    out[OUT_SCALARS + wave] = v;
  }
}

// ------------------------------------------------------------- launch -----
extern "C" void kernel_launch(void* const* d_in, const int* in_sizes, int n_in,
                              void* d_out, int out_size, void* d_ws, size_t ws_size,
                              hipStream_t stream)
{
  const float* x      = (const float*)d_in[0];
  const float* wself  = (const float*)d_in[1];
  const float* wneigh = (const float*)d_in[2];
  const float* bvec   = (const float*)d_in[3];
  float* out = (float*)d_out;
  float* ws  = (float*)d_ws;

  float4* srec  = (float4*)ws;                      /* 8N floats          */
  int* bhistT   = (int*)(ws + 8 * NPART);           /* NBINS*NPREP ints   */
  int* binstart = bhistT + NBINS * NPREP;           /* NBINS+1 ints       */
  float* partials = (float*)(binstart + NBINS + 65);/* 6*SWBLK floats     */

  hipLaunchKernelGGL(hist_kernel, dim3(NPREP), dim3(256), 0, stream,
                     x, bhistT);
  hipLaunchKernelGGL(place_kernel, dim3(NPREP), dim3(256), 0, stream,
                     x, wneigh, bhistT, srec, binstart);
  hipLaunchKernelGGL(sweep_kernel, dim3(SWBLK), dim3(256), 0, stream,
                     x, wself, bvec, binstart, srec, out, partials);
  hipLaunchKernelGGL(reduce_kernel, dim3(1), dim3(384), 0, stream,
                     partials, out);
}